// Round 7
// baseline (225.056 us; speedup 1.0000x reference)
//
#include <hip/hip_runtime.h>
#include <hip/hip_bf16.h>
#include <math.h>

// Problem constants (B=2, I=8, J=1025, M=256, H=8, Dh=32)
#define BB   2
#define II   8
#define JJ   1025
#define MM   256
#define HH   8
#define DH   32
#define BI   (BB*II)          // 16
#define RTOT (BI*JJ)          // 16400 rows (tokens)
#define NQKV (3*MM)           // 768
#define HID  (4*MM)           // 1024
#define MPAD 16512            // 258*64

// FC GEMM tile: 64 x 128 x 32, 256 threads = 4 waves
#define BM 64
#define BN 128
#define BK 32
#define LP 40   // LDS pitch bf16 (80 B): 2-way bank alias = free, 16B aligned

#define WQN (NQKV*MM)         // 196608
#define W1N (HID*MM)          // 262144
#define W2N (MM*HID)          // 262144

typedef unsigned short ushort;
typedef __attribute__((ext_vector_type(8))) short short8;    // 8 bf16
typedef __attribute__((ext_vector_type(4))) float f32x4;
typedef __attribute__((ext_vector_type(4))) ushort ushort4v; // 4 bf16 (8 B)

__device__ __forceinline__ ushort f2bf(float x) {
    __hip_bfloat16 h = __float2bfloat16(x);
    return *reinterpret_cast<ushort*>(&h);
}
__device__ __forceinline__ float bf2f(ushort u) {
    __hip_bfloat16 h = *reinterpret_cast<__hip_bfloat16*>(&u);
    return __bfloat162float(h);
}
__device__ __forceinline__ float gelu_exact(float x) {
    return 0.5f * x * (1.0f + erff(x * 0.70710678118654752f));
}
__device__ __forceinline__ float wave_sum(float v) {
#pragma unroll
    for (int off = 32; off > 0; off >>= 1) v += __shfl_xor(v, off);
    return v;
}
__device__ __forceinline__ float block_sum256(float v, float* red, int t) {
    red[t] = v; __syncthreads();
    for (int s = 128; s > 0; s >>= 1) {
        if (t < s) red[t] += red[t + s];
        __syncthreads();
    }
    float r = red[0]; __syncthreads();
    return r;
}

// ---------------------------------------------------------------------------
// K_prep: weight casts + Wo row-sums + Hbf pad zero + LN1 (fused)
// grid = 2816 (casts) + 256 (wosum) + 112 (Hbf pad) + 4128 (LN1) = 7312
// ---------------------------------------------------------------------------
__global__ __launch_bounds__(256) void k_prep(
    const float* __restrict__ wq, const float* __restrict__ w1,
    const float* __restrict__ w2, const float* __restrict__ Wo,
    const float* __restrict__ save, const float* __restrict__ g1,
    const float* __restrict__ b1,
    ushort* __restrict__ dq, ushort* __restrict__ d1, ushort* __restrict__ d2,
    float* __restrict__ woSum, ushort* __restrict__ Hbf,
    ushort* __restrict__ Ah)
{
    __shared__ float red[256];
    const int gb = blockIdx.x, t = threadIdx.x;
    if (gb < 2816) {
        int i = gb * 256 + t;
        if (i < WQN) dq[i] = f2bf(wq[i]);
        else if (i < WQN + W1N) d1[i - WQN] = f2bf(w1[i - WQN]);
        else d2[i - WQN - W1N] = f2bf(w2[i - WQN - W1N]);
    } else if (gb < 3072) {
        int m = gb - 2816;
        float s = block_sum256(Wo[m * MM + t], red, t);
        if (t == 0) woSum[m] = s;
    } else if (gb < 3184) {
        int row = RTOT + (gb - 3072);
        Hbf[(size_t)row * MM + t] = 0;
    } else {
        // LN1 + bf16 cast, wave per row
        const int wave = t >> 6, l = t & 63;
        const int row = (gb - 3184) * 4 + wave;
        const size_t base = (size_t)row * MM + 4 * l;
        if (row >= RTOT) { ushort4v z = 0; *(ushort4v*)&Ah[base] = z; return; }
        f32x4 v = *(const f32x4*)&save[base];
        float mu = wave_sum(v[0] + v[1] + v[2] + v[3]) * (1.0f / MM);
        f32x4 d;
#pragma unroll
        for (int c = 0; c < 4; ++c) d[c] = v[c] - mu;
        float var = wave_sum(d[0]*d[0] + d[1]*d[1] + d[2]*d[2] + d[3]*d[3]) * (1.0f / MM);
        float rstd = 1.0f / sqrtf(var + 1e-5f);
        f32x4 g = *(const f32x4*)&g1[4 * l];
        f32x4 b = *(const f32x4*)&b1[4 * l];
        ushort4v o;
#pragma unroll
        for (int c = 0; c < 4; ++c) o[c] = f2bf(d[c] * rstd * g[c] + b[c]);
        *(ushort4v*)&Ah[base] = o;
    }
}

// ---------------------------------------------------------------------------
// K_gram: G_bi[m][n] = sum_j Ah[bi,j,m]*Ah[bi,j,n]  (bf16 out, fp32 acc)
// grid (16 tiles of 64x64, 16 bi). K = 1025 (33 chunks of 32, guarded).
// LDS-transposed staging so MFMA k-dim (=j) is contiguous.
// ---------------------------------------------------------------------------
__global__ __launch_bounds__(256, 2) void k_gram(const ushort* __restrict__ Ah,
                                                 ushort* __restrict__ G) {
    __shared__ ushort As[2][64 * 40];
    __shared__ ushort Bs[2][64 * 40];
    const int tile = blockIdx.x, bi = blockIdx.y;
    const int m0 = (tile >> 2) * 64, n0 = (tile & 3) * 64;
    const int t = threadIdx.x, w = t >> 6, lane = t & 63;
    const int lrow = lane & 15, quad = lane >> 4;
    const int jj = t >> 3;          // 0..31 (j within chunk)
    const int mc = (t & 7) * 8;     // m-chunk offset
    const ushort* base = Ah + (size_t)bi * JJ * MM;

    f32x4 acc[4] = {};
    f32x4 ra, rb;

    auto loadAB = [&](int j0) {
        int j = j0 + jj;
        if (j < JJ) {
            ra = *(const f32x4*)(base + (size_t)j * MM + m0 + mc);
            rb = *(const f32x4*)(base + (size_t)j * MM + n0 + mc);
        } else { ra = f32x4{0,0,0,0}; rb = f32x4{0,0,0,0}; }
    };
    auto stage = [&](int buf) {
        const ushort* pa = (const ushort*)&ra;
        const ushort* pb = (const ushort*)&rb;
#pragma unroll
        for (int e = 0; e < 8; ++e) {
            As[buf][(mc + e) * 40 + jj] = pa[e];
            Bs[buf][(mc + e) * 40 + jj] = pb[e];
        }
    };

    loadAB(0);
    stage(0);
    const int NCK = 33;
    for (int ck = 0; ck < NCK; ++ck) {
        __syncthreads();
        const int cur = ck & 1, nxt = cur ^ 1;
        const bool more = (ck + 1 < NCK);
        if (more) loadAB((ck + 1) * 32);
        short8 fb = *(const short8*)&Bs[cur][(w * 16 + lrow) * 40 + quad * 8];
#pragma unroll
        for (int mt = 0; mt < 4; ++mt) {
            short8 fa = *(const short8*)&As[cur][(mt * 16 + lrow) * 40 + quad * 8];
            acc[mt] = __builtin_amdgcn_mfma_f32_16x16x32_bf16(fa, fb, acc[mt], 0, 0, 0);
        }
        if (more) stage(nxt);
    }
    // store bf16: row=quad*4+v (m), col=lrow (n)
#pragma unroll
    for (int mt = 0; mt < 4; ++mt)
#pragma unroll
        for (int v = 0; v < 4; ++v) {
            int m = m0 + mt * 16 + quad * 4 + v;
            int n = n0 + w * 16 + lrow;
            G[((size_t)bi * MM + m) * MM + n] = f2bf(acc[mt][v]);
        }
}

// ---------------------------------------------------------------------------
// K_weff: per (bi,h):  T1 = scale*Wk_h*G_bi  (MFMA, 32x256, K=256)
//                      KtV = T1*Wv_h^T        (VALU, 32x32)
//                      WeffT[n=h*32+d2][m] = sum_d1 Wq_h[d1,m]*KtV[d1,d2]
// grid = 128 blocks (bi*8+h).
// ---------------------------------------------------------------------------
__global__ __launch_bounds__(256, 1) void k_weff(const ushort* __restrict__ WqB,
                                                 const ushort* __restrict__ G,
                                                 ushort* __restrict__ WeffT) {
    __shared__ ushort T1s[32 * 264];
    __shared__ ushort WqS[32 * 264];
    __shared__ ushort WvS[32 * 264];
    __shared__ float  kv[32 * 33];

    const int bi = blockIdx.x >> 3, h = blockIdx.x & 7;
    const int t = threadIdx.x, w = t >> 6, lane = t & 63;
    const int lrow = lane & 15, quad = lane >> 4;
    const float scale = 0.17677669529663687f;  // 1/sqrt(32)

    // stage Wq_h and Wv_h rows into LDS (each thread: 32 bf16 = 4 x 16B)
    {
        int r = t >> 3, c = (t & 7) * 32;
#pragma unroll
        for (int e = 0; e < 4; ++e) {
            *(f32x4*)&WqS[r * 264 + c + e * 8] =
                *(const f32x4*)(WqB + (size_t)(h * DH + r) * MM + c + e * 8);
            *(f32x4*)&WvS[r * 264 + c + e * 8] =
                *(const f32x4*)(WqB + (size_t)(2 * MM + h * DH + r) * MM + c + e * 8);
        }
    }

    // T1 = Wk_h @ G_bi  (A,B frags direct from global; K=256 in 8 iters)
    f32x4 acc[2][4] = {};
    const ushort* wkbase = WqB + (size_t)(MM + h * DH) * MM;
    const ushort* gbase  = G + (size_t)bi * MM * MM;
    for (int kk = 0; kk < MM; kk += 32) {
        short8 fa[2], fb[4];
#pragma unroll
        for (int mt = 0; mt < 2; ++mt)
            fa[mt] = *(const short8*)(wkbase + (size_t)(mt * 16 + lrow) * MM + kk + quad * 8);
#pragma unroll
        for (int jt = 0; jt < 4; ++jt)
            fb[jt] = *(const short8*)(gbase + (size_t)((w * 4 + jt) * 16 + lrow) * MM + kk + quad * 8);
#pragma unroll
        for (int mt = 0; mt < 2; ++mt)
#pragma unroll
            for (int jt = 0; jt < 4; ++jt)
                acc[mt][jt] = __builtin_amdgcn_mfma_f32_16x16x32_bf16(
                    fa[mt], fb[jt], acc[mt][jt], 0, 0, 0);
    }
    // write T1 (with scale) to LDS: row=d1, col=n
#pragma unroll
    for (int mt = 0; mt < 2; ++mt)
#pragma unroll
        for (int jt = 0; jt < 4; ++jt)
#pragma unroll
            for (int v = 0; v < 4; ++v) {
                int d1 = mt * 16 + quad * 4 + v;
                int n  = (w * 4 + jt) * 16 + lrow;
                T1s[d1 * 264 + n] = f2bf(scale * acc[mt][jt][v]);
            }
    __syncthreads();

    // KtV[d1][d2] = sum_n T1[d1][n] * Wv[d2][n]
    {
        int d1 = t >> 3, d2b = (t & 7) * 4;
        float a4[4] = {0.f, 0.f, 0.f, 0.f};
        for (int n = 0; n < MM; ++n) {
            float tv = bf2f(T1s[d1 * 264 + n]);
#pragma unroll
            for (int e = 0; e < 4; ++e)
                a4[e] += tv * bf2f(WvS[(d2b + e) * 264 + n]);
        }
#pragma unroll
        for (int e = 0; e < 4; ++e) kv[d1 * 33 + d2b + e] = a4[e];
    }
    __syncthreads();

    // WeffT[h*32+d2][m] = sum_d1 Wq[d1][m] * KtV[d1][d2]
    {
        int d2 = t & 31, mb = (t >> 5) * 32;
        float kl[32];
#pragma unroll
        for (int d1 = 0; d1 < 32; ++d1) kl[d1] = kv[d1 * 33 + d2];
        ushort* outp = WeffT + ((size_t)bi * MM + h * DH + d2) * MM + mb;
        for (int m = 0; m < 32; ++m) {
            float s = 0.f;
#pragma unroll
            for (int d1 = 0; d1 < 32; ++d1)
                s += bf2f(WqS[d1 * 264 + mb + m]) * kl[d1];
            outp[m] = f2bf(s);
        }
    }
}

// ---------------------------------------------------------------------------
// K_attn: per (jb,bi): 32x256 tile of imv = Ah @ WeffT_bi^T(row-major n,k),
// epilogue s2 = woSum*imv + save, fused LN2 -> Hbf.  grid (33, 16).
// ---------------------------------------------------------------------------
__global__ __launch_bounds__(256, 2) void k_attn(
    const ushort* __restrict__ Ah, const ushort* __restrict__ WeffT,
    const float* __restrict__ woSum, const float* __restrict__ save,
    const float* __restrict__ g2, const float* __restrict__ b2,
    float* __restrict__ s2, ushort* __restrict__ Hbf)
{
    __shared__ __align__(16) ushort sA[2][32 * 40];
    __shared__ __align__(16) ushort sW[2][256 * 40];
    __shared__ float redS[32 * 4], redQ[32 * 4];

    const int jb = blockIdx.x, bi = blockIdx.y;
    const int t = threadIdx.x, w = t >> 6, lane = t & 63;
    const int lrow = lane & 15, quad = lane >> 4;
    const ushort* wbase = WeffT + (size_t)bi * MM * MM;
    const ushort* abase = Ah + (size_t)bi * JJ * MM;
    const int arow = (t & 127) >> 2, ak = (t & 3) * 8;
    const bool adut = (t < 128);
    const bool aval = adut && (jb * 32 + arow) < JJ;

    f32x4 rw[4], ra = {};
    auto loadW = [&](int kk) {
#pragma unroll
        for (int c = 0; c < 4; ++c)
            rw[c] = *(const f32x4*)(wbase + (size_t)t * MM + kk + c * 8);
        if (aval) ra = *(const f32x4*)(abase + (size_t)(jb * 32 + arow) * MM + kk + ak);
    };
    auto stage = [&](int buf) {
#pragma unroll
        for (int c = 0; c < 4; ++c)
            *(f32x4*)&sW[buf][t * 40 + c * 8] = rw[c];
        if (adut) *(f32x4*)&sA[buf][arow * 40 + ak] = adut && aval ? ra : f32x4{0,0,0,0};
    };

    f32x4 acc[2][4] = {};
    loadW(0);
    stage(0);
    for (int kt = 0; kt < 8; ++kt) {
        __syncthreads();
        const int cur = kt & 1, nxt = cur ^ 1;
        const bool more = (kt + 1 < 8);
        if (more) loadW((kt + 1) * 32);
        short8 fa[2], fw[4];
#pragma unroll
        for (int i = 0; i < 2; ++i)
            fa[i] = *(const short8*)&sA[cur][(i * 16 + lrow) * 40 + quad * 8];
#pragma unroll
        for (int jt = 0; jt < 4; ++jt)
            fw[jt] = *(const short8*)&sW[cur][(w * 64 + jt * 16 + lrow) * 40 + quad * 8];
#pragma unroll
        for (int i = 0; i < 2; ++i)
#pragma unroll
            for (int jt = 0; jt < 4; ++jt)
                acc[i][jt] = __builtin_amdgcn_mfma_f32_16x16x32_bf16(
                    fa[i], fw[jt], acc[i][jt], 0, 0, 0);
        if (more) stage(nxt);
    }

    // --- epilogue: c = woSum*acc + save;  LN2 over the full 256-wide row ---
    int   colv[4];
    float wos[4], gv[4], bv[4];
#pragma unroll
    for (int jt = 0; jt < 4; ++jt) {
        colv[jt] = w * 64 + jt * 16 + lrow;
        wos[jt] = woSum[colv[jt]];
        gv[jt]  = g2[colv[jt]];
        bv[jt]  = b2[colv[jt]];
    }

    float pS[8], pQ[8];
#pragma unroll
    for (int i = 0; i < 2; ++i)
#pragma unroll
        for (int v = 0; v < 4; ++v) {
            int jv = jb * 32 + i * 16 + quad * 4 + v;
            bool valid = jv < JJ;
            size_t rbase = ((size_t)bi * JJ + (valid ? jv : 0)) * MM;
            float s = 0.f, q = 0.f;
#pragma unroll
            for (int jt = 0; jt < 4; ++jt) {
                float c = 0.f;
                if (valid)
                    c = wos[jt] * acc[i][jt][v] + save[rbase + colv[jt]];
                acc[i][jt][v] = c;
                s += c; q += c * c;
            }
            // reduce over the 16 lrow lanes (stays within quad group)
#pragma unroll
            for (int off = 1; off < 16; off <<= 1) {
                s += __shfl_xor(s, off);
                q += __shfl_xor(q, off);
            }
            pS[i * 4 + v] = s; pQ[i * 4 + v] = q;
        }
    if (lrow == 0) {
#pragma unroll
        for (int i = 0; i < 2; ++i)
#pragma unroll
            for (int v = 0; v < 4; ++v) {
                int rl = i * 16 + quad * 4 + v;
                redS[rl * 4 + w] = pS[i * 4 + v];
                redQ[rl * 4 + w] = pQ[i * 4 + v];
            }
    }
    __syncthreads();
#pragma unroll
    for (int i = 0; i < 2; ++i)
#pragma unroll
        for (int v = 0; v < 4; ++v) {
            int rl = i * 16 + quad * 4 + v;
            int jv = jb * 32 + rl;
            if (jv >= JJ) continue;
            float sum = redS[rl * 4 + 0] + redS[rl * 4 + 1] + redS[rl * 4 + 2] + redS[rl * 4 + 3];
            float sq  = redQ[rl * 4 + 0] + redQ[rl * 4 + 1] + redQ[rl * 4 + 2] + redQ[rl * 4 + 3];
            float mu = sum * (1.0f / MM);
            float var = sq * (1.0f / MM) - mu * mu;
            float rstd = rsqrtf(var + 1e-5f);
            size_t rbase = ((size_t)bi * JJ + jv) * MM;
#pragma unroll
            for (int jt = 0; jt < 4; ++jt) {
                float c = acc[i][jt][v];
                s2[rbase + colv[jt]] = c;
                Hbf[rbase + colv[jt]] = f2bf((c - mu) * rstd * gv[jt] + bv[jt]);
            }
        }
}

// ---------------------------------------------------------------------------
// MFMA GEMM template (proven): 64x128x32, dbuf LDS + reg prefetch.
// FC1 (K=256, gelu->bf16), FC2 (K=1024, +b+s2->fp32).
// ---------------------------------------------------------------------------
template <bool GELU_EPI, bool ADD_EPI, bool STORE_BF16, bool GUARD_M>
__global__ __launch_bounds__(256, 4) void k_gemm(
    const ushort* __restrict__ A, const ushort* __restrict__ W,
    const float* __restrict__ bias, const float* __restrict__ addsrc,
    void* __restrict__ Cout, int ldc, int K, int Mrows)
{
    __shared__ __align__(16) ushort sA[2][BM * LP];
    __shared__ __align__(16) ushort sB[2][BN * LP];

    const int tid  = threadIdx.x;
    const int wave = tid >> 6;
    const int lane = tid & 63;
    const int lrow = lane & 15;
    const int quad = lane >> 4;
    const int row0 = blockIdx.y * BM;
    const int col0 = blockIdx.x * BN;
    const int ar = tid >> 2;
    const int ac = (tid & 3) * 8;
    const int KT = K / BK;

    f32x4 acc[4][2] = {};

    f32x4 ra, rb0, rb1;
    ra  = *(const f32x4*)(A + (size_t)(row0 + ar) * K + ac);
    rb0 = *(const f32x4*)(W + (size_t)(col0 + ar) * K + ac);
    rb1 = *(const f32x4*)(W + (size_t)(col0 + ar + 64) * K + ac);
    *(f32x4*)&sA[0][ar * LP + ac] = ra;
    *(f32x4*)&sB[0][ar * LP + ac] = rb0;
    *(f32x4*)&sB[0][(ar + 64) * LP + ac] = rb1;

    for (int kt = 0; kt < KT; ++kt) {
        __syncthreads();
        const int cur = kt & 1, nxt = cur ^ 1;
        const bool more = (kt + 1 < KT);
        if (more) {
            const int kk = (kt + 1) * BK;
            ra  = *(const f32x4*)(A + (size_t)(row0 + ar) * K + kk + ac);
            rb0 = *(const f32x4*)(W + (size_t)(col0 + ar) * K + kk + ac);
            rb1 = *(const f32x4*)(W + (size_t)(col0 + ar + 64) * K + kk + ac);
        }
        short8 fa[4], fb[2];
#pragma unroll
        for (int i = 0; i < 4; ++i)
            fa[i] = *(const short8*)&sA[cur][(i * 16 + lrow) * LP + quad * 8];
#pragma unroll
        for (int j = 0; j < 2; ++j)
            fb[j] = *(const short8*)&sB[cur][(wave * 32 + j * 16 + lrow) * LP + quad * 8];
#pragma unroll
        for (int i = 0; i < 4; ++i)
#pragma unroll
            for (int j = 0; j < 2; ++j)
                acc[i][j] = __builtin_amdgcn_mfma_f32_16x16x32_bf16(
                    fa[i], fb[j], acc[i][j], 0, 0, 0);
        if (more) {
            *(f32x4*)&sA[nxt][ar * LP + ac] = ra;
            *(f32x4*)&sB[nxt][ar * LP + ac] = rb0;
            *(f32x4*)&sB[nxt][(ar + 64) * LP + ac] = rb1;
        }
    }

#pragma unroll
    for (int i = 0; i < 4; ++i)
#pragma unroll
        for (int j = 0; j < 2; ++j) {
            const int ncol = col0 + wave * 32 + j * 16 + lrow;
            const float bv = bias ? bias[ncol] : 0.0f;
#pragma unroll
            for (int v = 0; v < 4; ++v) {
                const int r = row0 + i * 16 + quad * 4 + v;
                if (GUARD_M && r >= Mrows) continue;
                float c = acc[i][j][v] + bv;
                if (GELU_EPI) c = gelu_exact(c);
                if (ADD_EPI) c += addsrc[(size_t)r * ldc + ncol];
                if (STORE_BF16) ((ushort*)Cout)[(size_t)r * ldc + ncol] = f2bf(c);
                else            ((float*)Cout)[(size_t)r * ldc + ncol] = c;
            }
        }
}

// ---------------------------------------------------------------------------
extern "C" void kernel_launch(void* const* d_in, const int* in_sizes, int n_in,
                              void* d_out, int out_size, void* d_ws, size_t ws_size,
                              hipStream_t stream) {
    const float* savespace = (const float*)d_in[1];
    const float* Wqkv      = (const float*)d_in[2];   // [768][256]
    const float* Wo        = (const float*)d_in[3];
    const float* ln1_g     = (const float*)d_in[4];
    const float* ln1_b     = (const float*)d_in[5];
    const float* ln2_g     = (const float*)d_in[6];
    const float* ln2_b     = (const float*)d_in[7];
    const float* fc1_w     = (const float*)d_in[8];   // [1024][256]
    const float* fc1_b     = (const float*)d_in[9];
    const float* fc2_w     = (const float*)d_in[10];  // [256][1024]
    const float* fc2_b     = (const float*)d_in[11];
    float* out = (float*)d_out;

    // ---- workspace layout (~73 MB, no aliasing; ws is 256 MB) ----
    char* w = (char*)d_ws;
    ushort* Ah    = (ushort*)w;                                   //  8,454,144
    ushort* Gm    = (ushort*)(w + 8454144);                       //  2,097,152
    ushort* WeffT = (ushort*)(w + 8454144 + 2097152);             //  2,097,152
    float*  s2    = (float*) (w + 8454144 + 2097152*2);           // 16,908,288
    ushort* Hbf   = (ushort*)(w + 8454144 + 2097152*2 + 16908288);//  8,454,144
    ushort* T     = (ushort*)(w + 8454144 + 2097152*2 + 16908288 + 8454144); // 33,816,576
    char* c4 = w + 8454144 + 2097152*2 + 16908288 + 8454144 + 33816576;
    ushort* WqB   = (ushort*)c4;                                  //    393,216
    ushort* F1B   = (ushort*)(c4 + WQN * 2);                      //    524,288
    ushort* F2B   = (ushort*)(c4 + WQN * 2 + W1N * 2);            //    524,288
    float*  woSum = (float*) (c4 + WQN * 2 + W1N * 2 + W2N * 2);

    // 1) prep: casts + wosum + Hbf pad zero + LN1
    k_prep<<<3184 + MPAD / 4, 256, 0, stream>>>(
        Wqkv, fc1_w, fc2_w, Wo, savespace, ln1_g, ln1_b,
        WqB, F1B, F2B, woSum, Hbf, Ah);
    // 2) Gram matrices G_bi = Ah_bi^T Ah_bi   grid(16,16)
    {
        dim3 grid(16, BI);
        k_gram<<<grid, 256, 0, stream>>>(Ah, Gm);
    }
    // 3) Weff per (bi,h)
    k_weff<<<BI * HH, 256, 0, stream>>>(WqB, Gm, WeffT);
    // 4) attn: imv GEMM + s2 + LN2 -> Hbf   grid(33,16)
    {
        dim3 grid(33, BI);
        k_attn<<<grid, 256, 0, stream>>>(Ah, WeffT, woSum, savespace,
                                         ln2_g, ln2_b, s2, Hbf);
    }
    // 5) T = gelu(Hbf @ F1^T + b1) -> bf16   grid(8, 258)
    {
        dim3 grid(HID / BN, MPAD / BM);
        k_gemm<true, false, true, false><<<grid, 256, 0, stream>>>(
            Hbf, F1B, fc1_b, nullptr, T, HID, MM, RTOT);
    }
    // 6) out = T @ F2^T + b2 + s2  (fp32)   grid(2, 258)
    {
        dim3 grid(MM / BN, MPAD / BM);
        k_gemm<false, true, false, true><<<grid, 256, 0, stream>>>(
            T, F2B, fc2_b, s2, out, MM, HID, RTOT);
    }
}